// Round 1
// baseline (743.318 us; speedup 1.0000x reference)
//
#include <hip/hip_runtime.h>
#include <hip/hip_bf16.h>
#include <stdint.h>

#define NC 2112   // H*DK*2 + DK = 16*64*2 + 64

typedef __attribute__((ext_vector_type(8))) short bf16x8;
typedef __attribute__((ext_vector_type(4))) float f32x4;

static __device__ __forceinline__ unsigned short f2bf(float f) {
  uint32_t u = __builtin_bit_cast(uint32_t, f);
  u += 0x7FFFu + ((u >> 16) & 1u);
  return (unsigned short)(u >> 16);
}
static __device__ __forceinline__ float bf2f(unsigned short u) {
  return __builtin_bit_cast(float, ((uint32_t)u) << 16);
}

// ---------------- 1. q fp32 -> bf16 ----------------
__global__ void k_convert_q(const float* __restrict__ q, unsigned short* __restrict__ qbf) {
  int i = blockIdx.x * blockDim.x + threadIdx.x;   // one float4 each; 2,097,152 total
  float4 v = ((const float4*)q)[i];
  ushort4 o;
  o.x = f2bf(v.x); o.y = f2bf(v.y); o.z = f2bf(v.z); o.w = f2bf(v.w);
  ((ushort4*)qbf)[i] = o;
}

// ---------------- 2. build WcatT[2112][1024] bf16 (N-major, k contiguous) ----------------
__global__ void k_build_wcatT(const float* __restrict__ Wq, const float* __restrict__ Wk,
                              const float* __restrict__ Wv, unsigned short* __restrict__ wt) {
  int t = blockIdx.x * blockDim.x + threadIdx.x;   // c*128 + k/8 ; 270,336 total
  int c = t >> 7;
  int k0 = (t & 127) << 3;
  unsigned short o[8];
#pragma unroll
  for (int i = 0; i < 8; ++i) {
    int k = k0 + i;
    float v;
    if (c < 1024)      v = Wq[((size_t)(c >> 6) * 1024 + k) * 64 + (c & 63)];
    else if (c < 2048) v = Wk[((size_t)((c - 1024) >> 6) * 1024 + k) * 64 + (c & 63)];
    else               v = Wv[(size_t)k * 64 + (c - 2048)];
    o[i] = f2bf(v);
  }
  *(ushort4*)&wt[(size_t)c * 1024 + k0]     = *(ushort4*)&o[0];
  *(ushort4*)&wt[(size_t)c * 1024 + k0 + 4] = *(ushort4*)&o[4];
}

// ---------------- 3. GEMM: G[8192][2112] = qbf[8192][1024] x WcatT^T ----------------
__global__ __launch_bounds__(256) void k_gemm(const unsigned short* __restrict__ A,
                                              const unsigned short* __restrict__ Bt,
                                              unsigned short* __restrict__ C) {
  __shared__ unsigned short As[128][40];   // +8 pad: bank spread, 16B-aligned rows
  __shared__ unsigned short Bs[128][40];
  const int tn = blockIdx.x, tm = blockIdx.y;
  const int rowBase = tm * 128, colBase = tn * 128;
  const int t = threadIdx.x;
  const int wave = t >> 6, lane = t & 63;
  const int wm = wave >> 1, wn = wave & 1;
  const int l15 = lane & 15, l4 = lane >> 4;
  f32x4 acc[4][4] = {};
  for (int kt = 0; kt < 1024; kt += 32) {
#pragma unroll
    for (int L = 0; L < 2; ++L) {
      int idx = t + L * 256;
      int r = idx >> 2, cc = (idx & 3) * 8;
      *(float4*)&As[r][cc] = *(const float4*)&A[(size_t)(rowBase + r) * 1024 + kt + cc];
      int rb = colBase + r;
      float4 bv = {0.f, 0.f, 0.f, 0.f};
      if (rb < NC) bv = *(const float4*)&Bt[(size_t)rb * 1024 + kt + cc];
      *(float4*)&Bs[r][cc] = bv;
    }
    __syncthreads();
    bf16x8 af[4], bfr[4];
#pragma unroll
    for (int m = 0; m < 4; ++m) af[m] = *(const bf16x8*)&As[wm * 64 + m * 16 + l15][l4 * 8];
#pragma unroll
    for (int n = 0; n < 4; ++n) bfr[n] = *(const bf16x8*)&Bs[wn * 64 + n * 16 + l15][l4 * 8];
#pragma unroll
    for (int m = 0; m < 4; ++m)
#pragma unroll
      for (int n = 0; n < 4; ++n)
        acc[m][n] = __builtin_amdgcn_mfma_f32_16x16x32_bf16(af[m], bfr[n], acc[m][n], 0, 0, 0);
    __syncthreads();
  }
#pragma unroll
  for (int m = 0; m < 4; ++m)
#pragma unroll
    for (int n = 0; n < 4; ++n) {
      int col = colBase + wn * 64 + n * 16 + l15;
      if (col < NC) {
        int row0 = rowBase + wm * 64 + m * 16 + l4 * 4;
#pragma unroll
        for (int i = 0; i < 4; ++i)
          C[(size_t)(row0 + i) * NC + col] = f2bf(acc[m][n][i]);
      }
    }
}

// ---------------- 4. vst[b][64][1024] = G[b*1024+j][2048+d] ----------------
__global__ void k_transpose_v(const unsigned short* __restrict__ G, unsigned short* __restrict__ vst) {
  int t = blockIdx.x * blockDim.x + threadIdx.x;  // 524,288
  int d = t & 63;
  int j = (t >> 6) & 1023;
  int b = t >> 16;
  vst[(size_t)(b * 64 + d) * 1024 + j] = G[(size_t)(b * 1024 + j) * NC + 2048 + d];
}

// ---------------- 5. attention ----------------
__global__ __launch_bounds__(512) void k_attn(const unsigned short* __restrict__ G,
                                              const unsigned short* __restrict__ vst,
                                              float* __restrict__ attn,
                                              float* __restrict__ head) {
  __shared__ unsigned short Qs[32][72];
  __shared__ unsigned short Ks[128][72];
  __shared__ unsigned short SP[32][1032];   // scores then P, bf16
  __shared__ float Osum[32][64];
  const int qt = blockIdx.x, b = blockIdx.y, h = blockIdx.z;
  const int t = threadIdx.x, wave = t >> 6, lane = t & 63;
  const int l15 = lane & 15, l4 = lane >> 4;

  for (int i = t; i < 32 * 64; i += 512) ((float*)Osum)[i] = 0.0f;
  if (t < 256) {
    int r = t >> 3, cc = (t & 7) * 8;
    *(float4*)&Qs[r][cc] =
        *(const float4*)&G[(size_t)(b * 1024 + qt * 32 + r) * NC + h * 64 + cc];
  }
  __syncthreads();

  const float scale = 0.125f;  // 1/sqrt(64)
  for (int ch = 0; ch < 8; ++ch) {
#pragma unroll
    for (int L = 0; L < 2; ++L) {
      int idx = t + L * 512;
      int r = idx >> 3, cc = (idx & 7) * 8;
      *(float4*)&Ks[r][cc] =
          *(const float4*)&G[(size_t)(b * 1024 + ch * 128 + r) * NC + 1024 + h * 64 + cc];
    }
    __syncthreads();
    f32x4 sacc[2] = {};
#pragma unroll
    for (int ks = 0; ks < 2; ++ks) {
      bf16x8 bk = *(const bf16x8*)&Ks[wave * 16 + l15][ks * 32 + l4 * 8];
#pragma unroll
      for (int m = 0; m < 2; ++m) {
        bf16x8 aq = *(const bf16x8*)&Qs[m * 16 + l15][ks * 32 + l4 * 8];
        sacc[m] = __builtin_amdgcn_mfma_f32_16x16x32_bf16(aq, bk, sacc[m], 0, 0, 0);
      }
    }
#pragma unroll
    for (int m = 0; m < 2; ++m)
#pragma unroll
      for (int i = 0; i < 4; ++i)
        SP[m * 16 + l4 * 4 + i][ch * 128 + wave * 16 + l15] = f2bf(sacc[m][i] * scale);
    __syncthreads();
  }

  // softmax: each wave owns rows {wave, wave+8, wave+16, wave+24}; full-wave reductions
  size_t attn_base = ((size_t)(h * 8 + b) * 1024 + (size_t)qt * 32) * 1024;
  for (int rr = 0; rr < 4; ++rr) {
    int row = rr * 8 + wave;
    float sv[16];
    float mx = -1e30f;
#pragma unroll
    for (int c = 0; c < 4; ++c) {
      uint2 u = *(const uint2*)&SP[row][c * 256 + lane * 4];
      sv[c * 4 + 0] = bf2f((unsigned short)(u.x & 0xFFFF));
      sv[c * 4 + 1] = bf2f((unsigned short)(u.x >> 16));
      sv[c * 4 + 2] = bf2f((unsigned short)(u.y & 0xFFFF));
      sv[c * 4 + 3] = bf2f((unsigned short)(u.y >> 16));
      mx = fmaxf(mx, fmaxf(fmaxf(sv[c*4+0], sv[c*4+1]), fmaxf(sv[c*4+2], sv[c*4+3])));
    }
#pragma unroll
    for (int off = 32; off > 0; off >>= 1) mx = fmaxf(mx, __shfl_xor(mx, off));
    float sum = 0.f;
#pragma unroll
    for (int i = 0; i < 16; ++i) { sv[i] = __expf(sv[i] - mx); sum += sv[i]; }
#pragma unroll
    for (int off = 32; off > 0; off >>= 1) sum += __shfl_xor(sum, off);
    float inv = 1.0f / sum;
#pragma unroll
    for (int c = 0; c < 4; ++c) {
      float4 p;
      p.x = sv[c*4+0] * inv; p.y = sv[c*4+1] * inv;
      p.z = sv[c*4+2] * inv; p.w = sv[c*4+3] * inv;
      *(float4*)&attn[attn_base + (size_t)row * 1024 + c * 256 + lane * 4] = p;
      uint2 o;
      o.x = (uint32_t)f2bf(p.x) | ((uint32_t)f2bf(p.y) << 16);
      o.y = (uint32_t)f2bf(p.z) | ((uint32_t)f2bf(p.w) << 16);
      *(uint2*)&SP[row][c * 256 + lane * 4] = o;
    }
  }
  __syncthreads();

  // PV: wave handles j-range [wave*128, wave*128+128)
  f32x4 oacc[2][4] = {};
  const unsigned short* vb = vst + (size_t)b * 64 * 1024;
#pragma unroll
  for (int js = 0; js < 4; ++js) {
    int j0 = wave * 128 + js * 32;
    bf16x8 ap[2];
#pragma unroll
    for (int m = 0; m < 2; ++m) ap[m] = *(const bf16x8*)&SP[m * 16 + l15][j0 + l4 * 8];
#pragma unroll
    for (int n = 0; n < 4; ++n) {
      bf16x8 bv = *(const bf16x8*)&vb[(size_t)(n * 16 + l15) * 1024 + j0 + l4 * 8];
#pragma unroll
      for (int m = 0; m < 2; ++m)
        oacc[m][n] = __builtin_amdgcn_mfma_f32_16x16x32_bf16(ap[m], bv, oacc[m][n], 0, 0, 0);
    }
  }
#pragma unroll
  for (int m = 0; m < 2; ++m)
#pragma unroll
    for (int n = 0; n < 4; ++n)
#pragma unroll
      for (int i = 0; i < 4; ++i)
        atomicAdd(&Osum[m * 16 + l4 * 4 + i][n * 16 + l15], oacc[m][n][i]);
  __syncthreads();
  for (int i = t; i < 32 * 64; i += 512) {
    int r = i >> 6, d = i & 63;
    head[((size_t)(h * 8 + b) * 1024 + qt * 32 + r) * 64 + d] = Osum[r][d];
  }
}

// ---------------- 6. pooled = mean over heads ----------------
__global__ void k_pooled(const float* __restrict__ head, float* __restrict__ pooled) {
  int i = blockIdx.x * blockDim.x + threadIdx.x;  // one float4; 131,072 total
  int r = i >> 4;
  int k4 = (i & 15) * 4;
  float4 acc = {0.f, 0.f, 0.f, 0.f};
#pragma unroll
  for (int h = 0; h < 16; ++h) {
    float4 v = *(const float4*)&head[((size_t)h * 8192 + r) * 64 + k4];
    acc.x += v.x; acc.y += v.y; acc.z += v.z; acc.w += v.w;
  }
  const float s = 1.0f / 16.0f;
  acc.x *= s; acc.y *= s; acc.z *= s; acc.w *= s;
  *(float4*)&pooled[(size_t)r * 64 + k4] = acc;
}

// ---------------- 7. out = pooled @ Wo (fp32) ----------------
__global__ __launch_bounds__(256) void k_final(const float* __restrict__ pooled,
                                               const float* __restrict__ Wo,
                                               float* __restrict__ out) {
  __shared__ float Ps[64][64];
  __shared__ float Ws[64][132];
  const int dt = blockIdx.x, rt = blockIdx.y;
  const int r0 = rt * 64, d0 = dt * 128;
  const int t = threadIdx.x;
#pragma unroll
  for (int j = 0; j < 4; ++j) {
    int e = t + j * 256;
    int r = e >> 4, k4 = (e & 15) * 4;
    *(float4*)&Ps[r][k4] = *(const float4*)&pooled[(size_t)(r0 + r) * 64 + k4];
  }
#pragma unroll
  for (int j = 0; j < 8; ++j) {
    int e = t + j * 256;
    int k = e >> 5, c4 = (e & 31) * 4;
    *(float4*)&Ws[k][c4] = *(const float4*)&Wo[(size_t)k * 1024 + d0 + c4];
  }
  __syncthreads();
  const int ty = t >> 4, tx = t & 15;
  float acc[4][8] = {};
  for (int k = 0; k < 64; ++k) {
    float a_[4], b_[8];
#pragma unroll
    for (int i = 0; i < 4; ++i) a_[i] = Ps[ty * 4 + i][k];
#pragma unroll
    for (int j = 0; j < 8; ++j) b_[j] = Ws[k][tx * 8 + j];
#pragma unroll
    for (int i = 0; i < 4; ++i)
#pragma unroll
      for (int j = 0; j < 8; ++j) acc[i][j] += a_[i] * b_[j];
  }
#pragma unroll
  for (int i = 0; i < 4; ++i) {
    float4 v0 = {acc[i][0], acc[i][1], acc[i][2], acc[i][3]};
    float4 v1 = {acc[i][4], acc[i][5], acc[i][6], acc[i][7]};
    size_t o = (size_t)(r0 + ty * 4 + i) * 1024 + d0 + tx * 8;
    *(float4*)&out[o]     = v0;
    *(float4*)&out[o + 4] = v1;
  }
}

extern "C" void kernel_launch(void* const* d_in, const int* in_sizes, int n_in,
                              void* d_out, int out_size, void* d_ws, size_t ws_size,
                              hipStream_t stream) {
  const float* q  = (const float*)d_in[0];
  // d_in[1] (k), d_in[2] (v) are unused by the reference
  const float* Wq = (const float*)d_in[3];
  const float* Wk = (const float*)d_in[4];
  const float* Wv = (const float*)d_in[5];
  const float* Wo = (const float*)d_in[6];

  char* ws = (char*)d_ws;
  unsigned short* qbf   = (unsigned short*)(ws + 0);          // 16,777,216 B
  unsigned short* wcatT = (unsigned short*)(ws + 16777216);   //  4,325,376 B
  unsigned short* G     = (unsigned short*)(ws + 21102592);   // 34,603,008 B
  unsigned short* vst   = (unsigned short*)(ws + 55705600);   //  1,048,576 B
  float*          head  = (float*)(ws + 56754176);            // 33,554,432 B
  float*          pooled= (float*)(ws + 90308608);            //  2,097,152 B

  float* out  = (float*)d_out;
  float* attn = out + (size_t)8 * 1024 * 1024;

  hipLaunchKernelGGL(k_convert_q,   dim3(8192),       dim3(256), 0, stream, q, qbf);
  hipLaunchKernelGGL(k_build_wcatT, dim3(1056),       dim3(256), 0, stream, Wq, Wk, Wv, wcatT);
  hipLaunchKernelGGL(k_gemm,        dim3(17, 64),     dim3(256), 0, stream, qbf, wcatT, G);
  hipLaunchKernelGGL(k_transpose_v, dim3(2048),       dim3(256), 0, stream, G, vst);
  hipLaunchKernelGGL(k_attn,        dim3(32, 8, 16),  dim3(512), 0, stream, G, vst, attn, head);
  hipLaunchKernelGGL(k_pooled,      dim3(512),        dim3(256), 0, stream, head, pooled);
  hipLaunchKernelGGL(k_final,       dim3(8, 128),     dim3(256), 0, stream, pooled, Wo, out);
}

// Round 2
// 390.860 us; speedup vs baseline: 1.9017x; 1.9017x over previous
//
#include <hip/hip_runtime.h>
#include <hip/hip_bf16.h>
#include <stdint.h>

#define NC 2112   // H*DK*2 + DK = 16*64*2 + 64

typedef __attribute__((ext_vector_type(8))) short bf16x8;
typedef __attribute__((ext_vector_type(4))) float f32x4;

static __device__ __forceinline__ unsigned short f2bf(float f) {
  uint32_t u = __builtin_bit_cast(uint32_t, f);
  u += 0x7FFFu + ((u >> 16) & 1u);
  return (unsigned short)(u >> 16);
}
static __device__ __forceinline__ float bf2f(unsigned short u) {
  return __builtin_bit_cast(float, ((uint32_t)u) << 16);
}
static __device__ __forceinline__ void gload16(const unsigned short* g, unsigned short* l) {
  __builtin_amdgcn_global_load_lds((const __attribute__((address_space(1))) void*)g,
                                   (__attribute__((address_space(3))) void*)l, 16, 0, 0);
}

// ---------------- 1. q fp32 -> bf16 ----------------
__global__ void k_convert_q(const float* __restrict__ q, unsigned short* __restrict__ qbf) {
  int i = blockIdx.x * blockDim.x + threadIdx.x;   // one float4 each; 2,097,152 total
  float4 v = ((const float4*)q)[i];
  ushort4 o;
  o.x = f2bf(v.x); o.y = f2bf(v.y); o.z = f2bf(v.z); o.w = f2bf(v.w);
  ((ushort4*)qbf)[i] = o;
}

// ---------------- 2. build WcatT[2112][1024] bf16 (N-major, k contiguous) ----------------
__global__ void k_build_wcatT(const float* __restrict__ Wq, const float* __restrict__ Wk,
                              const float* __restrict__ Wv, unsigned short* __restrict__ wt) {
  int t = blockIdx.x * blockDim.x + threadIdx.x;   // c*128 + k/8 ; 270,336 total
  int c = t >> 7;
  int k0 = (t & 127) << 3;
  unsigned short o[8];
#pragma unroll
  for (int i = 0; i < 8; ++i) {
    int k = k0 + i;
    float v;
    if (c < 1024)      v = Wq[((size_t)(c >> 6) * 1024 + k) * 64 + (c & 63)];
    else if (c < 2048) v = Wk[((size_t)((c - 1024) >> 6) * 1024 + k) * 64 + (c & 63)];
    else               v = Wv[(size_t)k * 64 + (c - 2048)];
    o[i] = f2bf(v);
  }
  *(ushort4*)&wt[(size_t)c * 1024 + k0]     = *(ushort4*)&o[0];
  *(ushort4*)&wt[(size_t)c * 1024 + k0 + 4] = *(ushort4*)&o[4];
}

// ---------------- 3. GEMM: G[8192][2112] = qbf[8192][1024] x WcatT^T (m97 pattern) ----------------
__global__ __launch_bounds__(256) void k_gemm(const unsigned short* __restrict__ A,
                                              const unsigned short* __restrict__ Bt,
                                              unsigned short* __restrict__ C) {
  __shared__ unsigned short As[128 * 32];   // linear: required by global_load_lds
  __shared__ unsigned short Bs[128 * 32];
  const int tn = blockIdx.x, tm = blockIdx.y;
  const int rowBase = tm * 128, colBase = tn * 128;
  const int t = threadIdx.x;
  const int wave = t >> 6, lane = t & 63;
  const int wm = wave >> 1, wn = wave & 1;
  const int l15 = lane & 15, l4 = lane >> 4;
  f32x4 acc[4][4] = {};
  for (int kt = 0; kt < 1024; kt += 32) {
#pragma unroll
    for (int i = 0; i < 2; ++i) {
      int e = (t + i * 256) * 8;          // elem index in 128x32 tile
      int r = e >> 5, c = e & 31;
      gload16(&A[(size_t)(rowBase + r) * 1024 + kt + c], &As[e]);
      int rb = colBase + r; rb = rb < NC ? rb : (NC - 1);   // clamp (dup row, never stored)
      gload16(&Bt[(size_t)rb * 1024 + kt + c], &Bs[e]);
    }
    __syncthreads();
    bf16x8 af[4], bfr[4];
#pragma unroll
    for (int m = 0; m < 4; ++m) af[m] = *(const bf16x8*)&As[(wm * 64 + m * 16 + l15) * 32 + l4 * 8];
#pragma unroll
    for (int n = 0; n < 4; ++n) bfr[n] = *(const bf16x8*)&Bs[(wn * 64 + n * 16 + l15) * 32 + l4 * 8];
#pragma unroll
    for (int m = 0; m < 4; ++m)
#pragma unroll
      for (int n = 0; n < 4; ++n)
        acc[m][n] = __builtin_amdgcn_mfma_f32_16x16x32_bf16(af[m], bfr[n], acc[m][n], 0, 0, 0);
    __syncthreads();
  }
#pragma unroll
  for (int m = 0; m < 4; ++m)
#pragma unroll
    for (int n = 0; n < 4; ++n) {
      int col = colBase + wn * 64 + n * 16 + l15;
      if (col < NC) {
        int row0 = rowBase + wm * 64 + m * 16 + l4 * 4;
#pragma unroll
        for (int i = 0; i < 4; ++i)
          C[(size_t)(row0 + i) * NC + col] = f2bf(acc[m][n][i]);
      }
    }
}

// ---------------- 4. vst[b][64][1024] = G[b*1024+j][2048+d] ----------------
__global__ void k_transpose_v(const unsigned short* __restrict__ G, unsigned short* __restrict__ vst) {
  int t = blockIdx.x * blockDim.x + threadIdx.x;  // 524,288
  int d = t & 63;
  int j = (t >> 6) & 1023;
  int b = t >> 16;
  vst[(size_t)(b * 64 + d) * 1024 + j] = G[(size_t)(b * 1024 + j) * NC + 2048 + d];
}

// ---------------- 5. attention: 1 block per (qt,b,h); no K/V LDS staging ----------------
__global__ __launch_bounds__(512, 4) void k_attn(const unsigned short* __restrict__ G,
                                                 const unsigned short* __restrict__ vst,
                                                 float* __restrict__ attn,
                                                 float* __restrict__ head) {
  __shared__ unsigned short SP[32][1032];  // scores then P (bf16); odd stride spreads banks
  const int qt = blockIdx.x, b = blockIdx.y, h = blockIdx.z;
  const int t = threadIdx.x, wave = t >> 6, lane = t & 63;
  const int l15 = lane & 15, l4 = lane >> 4;

  const unsigned short* Gb = G + (size_t)b * 1024 * NC;

  // Q fragments in registers: rows qt*32 + m*16 + l15, cols h*64 + ks*32 + l4*8
  bf16x8 qf[2][2];
#pragma unroll
  for (int m = 0; m < 2; ++m)
#pragma unroll
    for (int ks = 0; ks < 2; ++ks)
      qf[m][ks] = *(const bf16x8*)&Gb[(size_t)(qt * 32 + m * 16 + l15) * NC + h * 64 + ks * 32 + l4 * 8];

  // ---- QK^T: wave owns keys [wave*128, wave*128+128) ----
  const float scale = 0.125f;  // 1/sqrt(64)
#pragma unroll
  for (int half = 0; half < 2; ++half) {
    bf16x8 kf[4][2];
#pragma unroll
    for (int kt = 0; kt < 4; ++kt) {
      int k0 = wave * 128 + (half * 4 + kt) * 16;
#pragma unroll
      for (int ks = 0; ks < 2; ++ks)
        kf[kt][ks] = *(const bf16x8*)&Gb[(size_t)(k0 + l15) * NC + 1024 + h * 64 + ks * 32 + l4 * 8];
    }
#pragma unroll
    for (int kt = 0; kt < 4; ++kt) {
      int k0 = wave * 128 + (half * 4 + kt) * 16;
      f32x4 s0 = {}, s1 = {};
      s0 = __builtin_amdgcn_mfma_f32_16x16x32_bf16(qf[0][0], kf[kt][0], s0, 0, 0, 0);
      s0 = __builtin_amdgcn_mfma_f32_16x16x32_bf16(qf[0][1], kf[kt][1], s0, 0, 0, 0);
      s1 = __builtin_amdgcn_mfma_f32_16x16x32_bf16(qf[1][0], kf[kt][0], s1, 0, 0, 0);
      s1 = __builtin_amdgcn_mfma_f32_16x16x32_bf16(qf[1][1], kf[kt][1], s1, 0, 0, 0);
#pragma unroll
      for (int i = 0; i < 4; ++i) {
        SP[l4 * 4 + i][k0 + l15]      = f2bf(s0[i] * scale);
        SP[16 + l4 * 4 + i][k0 + l15] = f2bf(s1[i] * scale);
      }
    }
  }
  __syncthreads();

  // ---- softmax: wave owns rows wave*4 .. wave*4+3; 16 scores per lane ----
  size_t attn_base = ((size_t)(h * 8 + b) * 1024 + (size_t)qt * 32) * 1024;
#pragma unroll
  for (int rr = 0; rr < 4; ++rr) {
    int row = wave * 4 + rr;
    float sv[16];
#pragma unroll
    for (int c = 0; c < 2; ++c) {
      uint4 u = *(const uint4*)&SP[row][c * 512 + lane * 8];
      sv[c*8+0] = bf2f((unsigned short)(u.x & 0xFFFF));
      sv[c*8+1] = bf2f((unsigned short)(u.x >> 16));
      sv[c*8+2] = bf2f((unsigned short)(u.y & 0xFFFF));
      sv[c*8+3] = bf2f((unsigned short)(u.y >> 16));
      sv[c*8+4] = bf2f((unsigned short)(u.z & 0xFFFF));
      sv[c*8+5] = bf2f((unsigned short)(u.z >> 16));
      sv[c*8+6] = bf2f((unsigned short)(u.w & 0xFFFF));
      sv[c*8+7] = bf2f((unsigned short)(u.w >> 16));
    }
    float mx = sv[0];
#pragma unroll
    for (int i = 1; i < 16; ++i) mx = fmaxf(mx, sv[i]);
#pragma unroll
    for (int off = 32; off > 0; off >>= 1) mx = fmaxf(mx, __shfl_xor(mx, off));
    float sum = 0.f;
#pragma unroll
    for (int i = 0; i < 16; ++i) { sv[i] = __expf(sv[i] - mx); sum += sv[i]; }
#pragma unroll
    for (int off = 32; off > 0; off >>= 1) sum += __shfl_xor(sum, off);
    float inv = 1.0f / sum;
#pragma unroll
    for (int c = 0; c < 2; ++c) {
      float4 p0 = {sv[c*8+0]*inv, sv[c*8+1]*inv, sv[c*8+2]*inv, sv[c*8+3]*inv};
      float4 p1 = {sv[c*8+4]*inv, sv[c*8+5]*inv, sv[c*8+6]*inv, sv[c*8+7]*inv};
      float* ab = &attn[attn_base + (size_t)row * 1024 + c * 512 + lane * 8];
      *(float4*)ab = p0;
      *(float4*)(ab + 4) = p1;
      uint4 o;
      o.x = (uint32_t)f2bf(p0.x) | ((uint32_t)f2bf(p0.y) << 16);
      o.y = (uint32_t)f2bf(p0.z) | ((uint32_t)f2bf(p0.w) << 16);
      o.z = (uint32_t)f2bf(p1.x) | ((uint32_t)f2bf(p1.y) << 16);
      o.w = (uint32_t)f2bf(p1.z) | ((uint32_t)f2bf(p1.w) << 16);
      *(uint4*)&SP[row][c * 512 + lane * 8] = o;
    }
  }
  __syncthreads();

  // ---- PV: wave owns one 16x16 output tile (wm = q-block, wn = d-block); full j in regs ----
  const int wm = wave >> 2, wn = wave & 3;
  const unsigned short* vb = vst + ((size_t)b * 64 + wn * 16 + l15) * 1024;
  const unsigned short* pr = &SP[wm * 16 + l15][0];
  f32x4 o0 = {}, o1 = {};
#pragma unroll 8
  for (int jt = 0; jt < 32; jt += 2) {
    bf16x8 pa0 = *(const bf16x8*)&pr[jt * 32 + l4 * 8];
    bf16x8 bv0 = *(const bf16x8*)&vb[jt * 32 + l4 * 8];
    o0 = __builtin_amdgcn_mfma_f32_16x16x32_bf16(pa0, bv0, o0, 0, 0, 0);
    bf16x8 pa1 = *(const bf16x8*)&pr[(jt + 1) * 32 + l4 * 8];
    bf16x8 bv1 = *(const bf16x8*)&vb[(jt + 1) * 32 + l4 * 8];
    o1 = __builtin_amdgcn_mfma_f32_16x16x32_bf16(pa1, bv1, o1, 0, 0, 0);
  }
  f32x4 oacc = o0 + o1;
  float* hb = head + (((size_t)(h * 8 + b) * 1024) + qt * 32 + wm * 16) * 64 + wn * 16;
#pragma unroll
  for (int i = 0; i < 4; ++i)
    hb[(size_t)(l4 * 4 + i) * 64 + l15] = oacc[i];
}

// ---------------- 6. pooled = mean over heads ----------------
__global__ void k_pooled(const float* __restrict__ head, float* __restrict__ pooled) {
  int i = blockIdx.x * blockDim.x + threadIdx.x;  // one float4; 131,072 total
  int r = i >> 4;
  int k4 = (i & 15) * 4;
  float4 acc = {0.f, 0.f, 0.f, 0.f};
#pragma unroll
  for (int h = 0; h < 16; ++h) {
    float4 v = *(const float4*)&head[((size_t)h * 8192 + r) * 64 + k4];
    acc.x += v.x; acc.y += v.y; acc.z += v.z; acc.w += v.w;
  }
  const float s = 1.0f / 16.0f;
  acc.x *= s; acc.y *= s; acc.z *= s; acc.w *= s;
  *(float4*)&pooled[(size_t)r * 64 + k4] = acc;
}

// ---------------- 7. out = pooled @ Wo (fp32) ----------------
__global__ __launch_bounds__(256) void k_final(const float* __restrict__ pooled,
                                               const float* __restrict__ Wo,
                                               float* __restrict__ out) {
  __shared__ float Ps[64][64];
  __shared__ float Ws[64][132];
  const int dt = blockIdx.x, rt = blockIdx.y;
  const int r0 = rt * 64, d0 = dt * 128;
  const int t = threadIdx.x;
#pragma unroll
  for (int j = 0; j < 4; ++j) {
    int e = t + j * 256;
    int r = e >> 4, k4 = (e & 15) * 4;
    *(float4*)&Ps[r][k4] = *(const float4*)&pooled[(size_t)(r0 + r) * 64 + k4];
  }
#pragma unroll
  for (int j = 0; j < 8; ++j) {
    int e = t + j * 256;
    int k = e >> 5, c4 = (e & 31) * 4;
    *(float4*)&Ws[k][c4] = *(const float4*)&Wo[(size_t)k * 1024 + d0 + c4];
  }
  __syncthreads();
  const int ty = t >> 4, tx = t & 15;
  float acc[4][8] = {};
  for (int k = 0; k < 64; ++k) {
    float a_[4], b_[8];
#pragma unroll
    for (int i = 0; i < 4; ++i) a_[i] = Ps[ty * 4 + i][k];
#pragma unroll
    for (int j = 0; j < 8; ++j) b_[j] = Ws[k][tx * 8 + j];
#pragma unroll
    for (int i = 0; i < 4; ++i)
#pragma unroll
      for (int j = 0; j < 8; ++j) acc[i][j] += a_[i] * b_[j];
  }
#pragma unroll
  for (int i = 0; i < 4; ++i) {
    float4 v0 = {acc[i][0], acc[i][1], acc[i][2], acc[i][3]};
    float4 v1 = {acc[i][4], acc[i][5], acc[i][6], acc[i][7]};
    size_t o = (size_t)(r0 + ty * 4 + i) * 1024 + d0 + tx * 8;
    *(float4*)&out[o]     = v0;
    *(float4*)&out[o + 4] = v1;
  }
}

extern "C" void kernel_launch(void* const* d_in, const int* in_sizes, int n_in,
                              void* d_out, int out_size, void* d_ws, size_t ws_size,
                              hipStream_t stream) {
  const float* q  = (const float*)d_in[0];
  // d_in[1] (k), d_in[2] (v) are unused by the reference
  const float* Wq = (const float*)d_in[3];
  const float* Wk = (const float*)d_in[4];
  const float* Wv = (const float*)d_in[5];
  const float* Wo = (const float*)d_in[6];

  char* ws = (char*)d_ws;
  unsigned short* qbf   = (unsigned short*)(ws + 0);          // 16,777,216 B
  unsigned short* wcatT = (unsigned short*)(ws + 16777216);   //  4,325,376 B
  unsigned short* G     = (unsigned short*)(ws + 21102592);   // 34,603,008 B
  unsigned short* vst   = (unsigned short*)(ws + 55705600);   //  1,048,576 B
  float*          head  = (float*)(ws + 56754176);            // 33,554,432 B
  float*          pooled= (float*)(ws + 90308608);            //  2,097,152 B

  float* out  = (float*)d_out;
  float* attn = out + (size_t)8 * 1024 * 1024;

  hipLaunchKernelGGL(k_convert_q,   dim3(8192),       dim3(256), 0, stream, q, qbf);
  hipLaunchKernelGGL(k_build_wcatT, dim3(1056),       dim3(256), 0, stream, Wq, Wk, Wv, wcatT);
  hipLaunchKernelGGL(k_gemm,        dim3(17, 64),     dim3(256), 0, stream, qbf, wcatT, G);
  hipLaunchKernelGGL(k_transpose_v, dim3(2048),       dim3(256), 0, stream, G, vst);
  hipLaunchKernelGGL(k_attn,        dim3(32, 8, 16),  dim3(512), 0, stream, G, vst, attn, head);
  hipLaunchKernelGGL(k_pooled,      dim3(512),        dim3(256), 0, stream, head, pooled);
  hipLaunchKernelGGL(k_final,       dim3(8, 128),     dim3(256), 0, stream, pooled, Wo, out);
}

// Round 4
// 354.906 us; speedup vs baseline: 2.0944x; 1.1013x over previous
//
#include <hip/hip_runtime.h>
#include <hip/hip_bf16.h>
#include <stdint.h>

#define NC 2112   // H*DK*2 + DK = 16*64*2 + 64

typedef __attribute__((ext_vector_type(8))) short bf16x8;
typedef __attribute__((ext_vector_type(4))) float f32x4;

static __device__ __forceinline__ unsigned short f2bf(float f) {
  uint32_t u = __builtin_bit_cast(uint32_t, f);
  u += 0x7FFFu + ((u >> 16) & 1u);
  return (unsigned short)(u >> 16);
}
static __device__ __forceinline__ float bf2f(unsigned short u) {
  return __builtin_bit_cast(float, ((uint32_t)u) << 16);
}
static __device__ __forceinline__ void gload16(const unsigned short* g, unsigned short* l) {
  __builtin_amdgcn_global_load_lds((const __attribute__((address_space(1))) void*)g,
                                   (__attribute__((address_space(3))) void*)l, 16, 0, 0);
}

// ---------------- 1. q fp32 -> bf16 ----------------
__global__ void k_convert_q(const float* __restrict__ q, unsigned short* __restrict__ qbf) {
  int i = blockIdx.x * blockDim.x + threadIdx.x;   // one float4 each; 2,097,152 total
  float4 v = ((const float4*)q)[i];
  ushort4 o;
  o.x = f2bf(v.x); o.y = f2bf(v.y); o.z = f2bf(v.z); o.w = f2bf(v.w);
  ((ushort4*)qbf)[i] = o;
}

// ---------------- 2. build WcatT[2112][1024] bf16 (N-major, k contiguous) ----------------
__global__ void k_build_wcatT(const float* __restrict__ Wq, const float* __restrict__ Wk,
                              const float* __restrict__ Wv, unsigned short* __restrict__ wt) {
  int t = blockIdx.x * blockDim.x + threadIdx.x;   // c*128 + k/8 ; 270,336 total
  int c = t >> 7;
  int k0 = (t & 127) << 3;
  unsigned short o[8];
#pragma unroll
  for (int i = 0; i < 8; ++i) {
    int k = k0 + i;
    float v;
    if (c < 1024)      v = Wq[((size_t)(c >> 6) * 1024 + k) * 64 + (c & 63)];
    else if (c < 2048) v = Wk[((size_t)((c - 1024) >> 6) * 1024 + k) * 64 + (c & 63)];
    else               v = Wv[(size_t)k * 64 + (c - 2048)];
    o[i] = f2bf(v);
  }
  *(ushort4*)&wt[(size_t)c * 1024 + k0]     = *(ushort4*)&o[0];
  *(ushort4*)&wt[(size_t)c * 1024 + k0 + 4] = *(ushort4*)&o[4];
}

// ---------------- 3. GEMM (m97 pattern) + fused V-transpose epilogue ----------------
__global__ __launch_bounds__(256) void k_gemm(const unsigned short* __restrict__ A,
                                              const unsigned short* __restrict__ Bt,
                                              unsigned short* __restrict__ C,
                                              unsigned short* __restrict__ vst) {
  __shared__ unsigned short As[128 * 32];   // linear: required by global_load_lds
  __shared__ unsigned short Bs[128 * 32];
  const int L = blockIdx.x;                 // XCD swizzle: 1088 = 8 * 136
  const int wi = (L & 7) * 136 + (L >> 3);
  const int tn = wi % 17, tm = wi / 17;
  const int rowBase = tm * 128, colBase = tn * 128;
  const int t = threadIdx.x;
  const int wave = t >> 6, lane = t & 63;
  const int wm = wave >> 1, wn = wave & 1;
  const int l15 = lane & 15, l4 = lane >> 4;
  f32x4 acc[4][4] = {};
  for (int kt = 0; kt < 1024; kt += 32) {
#pragma unroll
    for (int i = 0; i < 2; ++i) {
      int e = (t + i * 256) * 8;          // elem index in 128x32 tile
      int r = e >> 5, c = e & 31;
      gload16(&A[(size_t)(rowBase + r) * 1024 + kt + c], &As[e]);
      int rb = colBase + r; rb = rb < NC ? rb : (NC - 1);   // clamp (dup row, never stored)
      gload16(&Bt[(size_t)rb * 1024 + kt + c], &Bs[e]);
    }
    __syncthreads();
    bf16x8 af[4], bfr[4];
#pragma unroll
    for (int m = 0; m < 4; ++m) af[m] = *(const bf16x8*)&As[(wm * 64 + m * 16 + l15) * 32 + l4 * 8];
#pragma unroll
    for (int n = 0; n < 4; ++n) bfr[n] = *(const bf16x8*)&Bs[(wn * 64 + n * 16 + l15) * 32 + l4 * 8];
#pragma unroll
    for (int m = 0; m < 4; ++m)
#pragma unroll
      for (int n = 0; n < 4; ++n)
        acc[m][n] = __builtin_amdgcn_mfma_f32_16x16x32_bf16(af[m], bfr[n], acc[m][n], 0, 0, 0);
    __syncthreads();
  }
#pragma unroll
  for (int m = 0; m < 4; ++m)
#pragma unroll
    for (int n = 0; n < 4; ++n) {
      int col = colBase + wn * 64 + n * 16 + l15;
      int row0 = rowBase + wm * 64 + m * 16 + l4 * 4;
      if (col < 2048) {
#pragma unroll
        for (int i = 0; i < 4; ++i)
          C[(size_t)(row0 + i) * NC + col] = f2bf(acc[m][n][i]);
      } else if (col < NC) {
        // V columns: write transposed into vst[b][d][j]
        int d = col - 2048;
#pragma unroll
        for (int i = 0; i < 4; ++i) {
          int rg = row0 + i;
          vst[((size_t)(rg >> 10) * 64 + d) * 1024 + (rg & 1023)] = f2bf(acc[m][n][i]);
        }
      }
    }
}

// ---------------- 4. attention: exp-in-pass-1, no max, single barrier ----------------
__global__ __launch_bounds__(512, 4) void k_attn(const unsigned short* __restrict__ G,
                                                 const unsigned short* __restrict__ vst,
                                                 float* __restrict__ attn,
                                                 float* __restrict__ head) {
  __shared__ unsigned short SP[32][1032];  // unnormalized exp(scores), bf16
  __shared__ float rs[32][8];              // per-row partial sums, per wave
  const int L = blockIdx.x;                // XCD swizzle: 4096 = 8 * 512
  const int wi = (L & 7) * 512 + (L >> 3);
  const int qt = wi & 31, b = (wi >> 5) & 7, h = wi >> 8;
  const int t = threadIdx.x, wave = t >> 6, lane = t & 63;
  const int l15 = lane & 15, l4 = lane >> 4;

  const unsigned short* Gb = G + (size_t)b * 1024 * NC;

  // Q fragments: rows qt*32 + m*16 + l15, cols h*64 + ks*32 + l4*8
  bf16x8 qf[2][2];
#pragma unroll
  for (int m = 0; m < 2; ++m)
#pragma unroll
    for (int ks = 0; ks < 2; ++ks)
      qf[m][ks] = *(const bf16x8*)&Gb[(size_t)(qt * 32 + m * 16 + l15) * NC + h * 64 + ks * 32 + l4 * 8];

  // ---- QK^T (wave owns keys [wave*128, +128)): exp + partial row-sums fused ----
  const float scale = 0.125f;  // 1/sqrt(64)
  float psum[2][4] = {};
#pragma unroll
  for (int half = 0; half < 2; ++half) {
    bf16x8 kf[4][2];
#pragma unroll
    for (int kt = 0; kt < 4; ++kt) {
      int k0 = wave * 128 + (half * 4 + kt) * 16;
#pragma unroll
      for (int ks = 0; ks < 2; ++ks)
        kf[kt][ks] = *(const bf16x8*)&Gb[(size_t)(k0 + l15) * NC + 1024 + h * 64 + ks * 32 + l4 * 8];
    }
#pragma unroll
    for (int kt = 0; kt < 4; ++kt) {
      int k0 = wave * 128 + (half * 4 + kt) * 16;
      f32x4 s0 = {}, s1 = {};
      s0 = __builtin_amdgcn_mfma_f32_16x16x32_bf16(qf[0][0], kf[kt][0], s0, 0, 0, 0);
      s0 = __builtin_amdgcn_mfma_f32_16x16x32_bf16(qf[0][1], kf[kt][1], s0, 0, 0, 0);
      s1 = __builtin_amdgcn_mfma_f32_16x16x32_bf16(qf[1][0], kf[kt][0], s1, 0, 0, 0);
      s1 = __builtin_amdgcn_mfma_f32_16x16x32_bf16(qf[1][1], kf[kt][1], s1, 0, 0, 0);
#pragma unroll
      for (int i = 0; i < 4; ++i) {
        unsigned short u0 = f2bf(__expf(s0[i] * scale));
        unsigned short u1 = f2bf(__expf(s1[i] * scale));
        SP[l4 * 4 + i][k0 + l15]      = u0;
        SP[16 + l4 * 4 + i][k0 + l15] = u1;
        psum[0][i] += bf2f(u0);
        psum[1][i] += bf2f(u1);
      }
    }
  }
  // reduce partial sums across l15 (same rows within an l4 group)
#pragma unroll
  for (int off = 1; off < 16; off <<= 1)
#pragma unroll
    for (int m = 0; m < 2; ++m)
#pragma unroll
      for (int i = 0; i < 4; ++i)
        psum[m][i] += __shfl_xor(psum[m][i], off);
  if (l15 == 0) {
#pragma unroll
    for (int m = 0; m < 2; ++m)
#pragma unroll
      for (int i = 0; i < 4; ++i)
        rs[m * 16 + l4 * 4 + i][wave] = psum[m][i];
  }
  __syncthreads();

  // ---- per-row inverse sums ----
  const int wm = wave >> 2, wn = wave & 3;
  float winv[4], pinv[4];
#pragma unroll
  for (int rr = 0; rr < 4; ++rr) {
    int row = wave * 4 + rr;
    float4 a = *(const float4*)&rs[row][0];
    float4 c = *(const float4*)&rs[row][4];
    winv[rr] = 1.0f / (a.x + a.y + a.z + a.w + c.x + c.y + c.z + c.w);
  }
#pragma unroll
  for (int i = 0; i < 4; ++i) {
    int row = wm * 16 + l4 * 4 + i;
    float4 a = *(const float4*)&rs[row][0];
    float4 c = *(const float4*)&rs[row][4];
    pinv[i] = 1.0f / (a.x + a.y + a.z + a.w + c.x + c.y + c.z + c.w);
  }

  // ---- attn write (rows wave*4..+3): scale + nontemporal fp32 store ----
  size_t attn_base = ((size_t)(h * 8 + b) * 1024 + (size_t)qt * 32) * 1024;
#pragma unroll
  for (int rr = 0; rr < 4; ++rr) {
    int row = wave * 4 + rr;
    float inv = winv[rr];
#pragma unroll
    for (int c = 0; c < 2; ++c) {
      uint4 u = *(const uint4*)&SP[row][c * 512 + lane * 8];
      f32x4 p0 = {bf2f((unsigned short)(u.x & 0xFFFF)) * inv,
                  bf2f((unsigned short)(u.x >> 16)) * inv,
                  bf2f((unsigned short)(u.y & 0xFFFF)) * inv,
                  bf2f((unsigned short)(u.y >> 16)) * inv};
      f32x4 p1 = {bf2f((unsigned short)(u.z & 0xFFFF)) * inv,
                  bf2f((unsigned short)(u.z >> 16)) * inv,
                  bf2f((unsigned short)(u.w & 0xFFFF)) * inv,
                  bf2f((unsigned short)(u.w >> 16)) * inv};
      float* ab = &attn[attn_base + (size_t)row * 1024 + c * 512 + lane * 8];
      __builtin_nontemporal_store(p0, (f32x4*)ab);
      __builtin_nontemporal_store(p1, (f32x4*)(ab + 4));
    }
  }

  // ---- PV: wave owns 16x16 tile (wm,wn); unnormalized P, scale at end ----
  const unsigned short* vb = vst + ((size_t)b * 64 + wn * 16 + l15) * 1024;
  const unsigned short* pr = &SP[wm * 16 + l15][0];
  f32x4 o0 = {}, o1 = {};
#pragma unroll 8
  for (int jt = 0; jt < 32; jt += 2) {
    bf16x8 pa0 = *(const bf16x8*)&pr[jt * 32 + l4 * 8];
    bf16x8 bv0 = *(const bf16x8*)&vb[jt * 32 + l4 * 8];
    o0 = __builtin_amdgcn_mfma_f32_16x16x32_bf16(pa0, bv0, o0, 0, 0, 0);
    bf16x8 pa1 = *(const bf16x8*)&pr[(jt + 1) * 32 + l4 * 8];
    bf16x8 bv1 = *(const bf16x8*)&vb[(jt + 1) * 32 + l4 * 8];
    o1 = __builtin_amdgcn_mfma_f32_16x16x32_bf16(pa1, bv1, o1, 0, 0, 0);
  }
  float* hb = head + (((size_t)(h * 8 + b) * 1024) + qt * 32 + wm * 16) * 64 + wn * 16;
#pragma unroll
  for (int i = 0; i < 4; ++i)
    hb[(size_t)(l4 * 4 + i) * 64 + l15] = (o0[i] + o1[i]) * pinv[i];
}

// ---------------- 5. fused head-mean + out = pooled @ Wo ----------------
__global__ __launch_bounds__(256) void k_final(const float* __restrict__ head,
                                               const float* __restrict__ Wo,
                                               float* __restrict__ out) {
  __shared__ float Ps[32][68];
  __shared__ float Ws[64][132];
  const int rt = blockIdx.x;
  const int r0 = rt * 32;
  const int t = threadIdx.x;
#pragma unroll
  for (int j = 0; j < 2; ++j) {
    int e = t + j * 256;                  // 512 float4 slots = 32 rows x 16
    int r = e >> 4, k4 = (e & 15) * 4;
    float4 acc = {0.f, 0.f, 0.f, 0.f};
#pragma unroll
    for (int hh = 0; hh < 16; ++hh) {
      float4 v = *(const float4*)&head[((size_t)hh * 8192 + r0 + r) * 64 + k4];
      acc.x += v.x; acc.y += v.y; acc.z += v.z; acc.w += v.w;
    }
    const float s = 1.0f / 16.0f;
    Ps[r][k4] = acc.x * s; Ps[r][k4 + 1] = acc.y * s;
    Ps[r][k4 + 2] = acc.z * s; Ps[r][k4 + 3] = acc.w * s;
  }
  const int ty = t >> 4, tx = t & 15;
  for (int dt = 0; dt < 8; ++dt) {
    int d0 = dt * 128;
#pragma unroll
    for (int j = 0; j < 8; ++j) {
      int e = t + j * 256;
      int k = e >> 5, c4 = (e & 31) * 4;
      *(float4*)&Ws[k][c4] = *(const float4*)&Wo[(size_t)k * 1024 + d0 + c4];
    }
    __syncthreads();
    float acc[2][8] = {};
    for (int k = 0; k < 64; ++k) {
      float a0 = Ps[ty * 2][k], a1 = Ps[ty * 2 + 1][k];
      float4 b0 = *(const float4*)&Ws[k][tx * 8];
      float4 b1 = *(const float4*)&Ws[k][tx * 8 + 4];
      acc[0][0] += a0 * b0.x; acc[0][1] += a0 * b0.y; acc[0][2] += a0 * b0.z; acc[0][3] += a0 * b0.w;
      acc[0][4] += a0 * b1.x; acc[0][5] += a0 * b1.y; acc[0][6] += a0 * b1.z; acc[0][7] += a0 * b1.w;
      acc[1][0] += a1 * b0.x; acc[1][1] += a1 * b0.y; acc[1][2] += a1 * b0.z; acc[1][3] += a1 * b0.w;
      acc[1][4] += a1 * b1.x; acc[1][5] += a1 * b1.y; acc[1][6] += a1 * b1.z; acc[1][7] += a1 * b1.w;
    }
#pragma unroll
    for (int i = 0; i < 2; ++i) {
      float4 v0 = {acc[i][0], acc[i][1], acc[i][2], acc[i][3]};
      float4 v1 = {acc[i][4], acc[i][5], acc[i][6], acc[i][7]};
      size_t o = (size_t)(r0 + ty * 2 + i) * 1024 + d0 + tx * 8;
      *(float4*)&out[o]     = v0;
      *(float4*)&out[o + 4] = v1;
    }
    __syncthreads();
  }
}

extern "C" void kernel_launch(void* const* d_in, const int* in_sizes, int n_in,
                              void* d_out, int out_size, void* d_ws, size_t ws_size,
                              hipStream_t stream) {
  const float* q  = (const float*)d_in[0];
  // d_in[1] (k), d_in[2] (v) are unused by the reference
  const float* Wq = (const float*)d_in[3];
  const float* Wk = (const float*)d_in[4];
  const float* Wv = (const float*)d_in[5];
  const float* Wo = (const float*)d_in[6];

  char* ws = (char*)d_ws;
  unsigned short* qbf   = (unsigned short*)(ws + 0);          // 16,777,216 B
  unsigned short* wcatT = (unsigned short*)(ws + 16777216);   //  4,325,376 B
  unsigned short* G     = (unsigned short*)(ws + 21102592);   // 34,603,008 B
  unsigned short* vst   = (unsigned short*)(ws + 55705600);   //  1,048,576 B
  float*          head  = (float*)(ws + 56754176);            // 33,554,432 B

  float* out  = (float*)d_out;
  float* attn = out + (size_t)8 * 1024 * 1024;

  hipLaunchKernelGGL(k_convert_q,   dim3(8192), dim3(256), 0, stream, q, qbf);
  hipLaunchKernelGGL(k_build_wcatT, dim3(1056), dim3(256), 0, stream, Wq, Wk, Wv, wcatT);
  hipLaunchKernelGGL(k_gemm,        dim3(1088), dim3(256), 0, stream, qbf, wcatT, G, vst);
  hipLaunchKernelGGL(k_attn,        dim3(4096), dim3(512), 0, stream, G, vst, attn, head);
  hipLaunchKernelGGL(k_final,       dim3(256),  dim3(256), 0, stream, head, Wo, out);
}